// Round 1
// baseline (3094.730 us; speedup 1.0000x reference)
//
#include <hip/hip_runtime.h>

// EmformerAttention on MI355X — round 0: correctness-first fp32 baseline.
// U=512 B=16 D=512 H=8 HD=64 R=32 S=16 M=32 -> Q=560 KV=576 PE=1023 N=128
//
// Pipeline:
//   detect_mask (mask dtype sniffing: int32 / uint8 / float32)
//   gemm: query = [rc;utt;summ] @ Wq^T + bq            -> ws
//   gemm: kv    = [mem;rc;utt]  @ Wkv^T + bkv          -> d_out key/val slots (outputs 3,4)
//   gemm: posW  = pos_emb @ Wpos^T                     -> ws
//   attn: scores(AC + rel-shifted BD) -> mask/pad -> softmax -> @V -> attnT (ws)
//   gemm: out   = attnT @ Wo^T + bo (+clip rows>=8704) -> d_out outputs 0,1

#define NEG_INF_F (-100000000.0f)
#define SCALE_F   (0.125f)   // 64^-0.5

// ---------------------------------------------------------------------------
// Mask dtype detection: scan first 80640 32-bit words (= full buffer if uint8,
// prefix if int32/float32).
//   float32 storage -> words are 0x0 or 0x3F800000
//   int32   storage -> words are 0 or 1
//   uint8   storage -> packed 0/1 bytes; some word >1 with overwhelming prob.
__global__ void detect_mask_kernel(const unsigned int* __restrict__ m,
                                   int nwords, int* __restrict__ flagOut) {
    __shared__ int fF, fG;
    if (threadIdx.x == 0) { fF = 0; fG = 0; }
    __syncthreads();
    for (int i = threadIdx.x; i < nwords; i += blockDim.x) {
        unsigned int w = m[i];
        if (w == 0x3F800000u)      atomicOr(&fF, 1);
        else if (w > 1u)           atomicOr(&fG, 1);
    }
    __syncthreads();
    if (threadIdx.x == 0) *flagOut = fF ? 2 : (fG ? 1 : 0);
}

// ---------------------------------------------------------------------------
// C[r,c] = sum_k A[r,k] * W[c,k] (+bias[c]), K = 512 fixed.
// A rows gathered from up to 3 concatenated segments (row boundaries rb1,rb2).
// outMode 0: out0[r*Ncols+c], clamp(+-10) for r >= clampStart.
// outMode 1: split N=1024 -> c<512 to out0[r*512+c], else out1[r*512+c-512].
__global__ __launch_bounds__(256) void gemm_kernel(
    const float* __restrict__ a0, const float* __restrict__ a1,
    const float* __restrict__ a2,
    int rb1, int rb2, int Mrows,
    const float* __restrict__ W, const float* __restrict__ bias,
    float* __restrict__ out0, float* __restrict__ out1,
    int Ncols, int outMode, int clampStart)
{
    const int tid = threadIdx.x;
    const int tx = tid & 15, ty = tid >> 4;
    const int bm = blockIdx.y * 64, bn = blockIdx.x * 64;

    __shared__ float As[16][68];   // [k][m], +4 pad breaks bank conflicts
    __shared__ float Bs[16][68];   // [k][n]

    float acc[4][4] = {{0.f}};

    const int lrow = tid >> 2;        // 0..63
    const int lc4  = (tid & 3) * 4;   // 0,4,8,12

    for (int kt = 0; kt < 512; kt += 16) {
        // --- stage A tile (with 3-segment gather + row guard)
        float4 av = make_float4(0.f, 0.f, 0.f, 0.f);
        {
            int r = bm + lrow;
            if (r < Mrows) {
                const float* src;
                if (r < rb1)      src = a0 + (size_t)r * 512;
                else if (r < rb2) src = a1 + (size_t)(r - rb1) * 512;
                else              src = a2 + (size_t)(r - rb2) * 512;
                av = *(const float4*)(src + kt + lc4);
            }
        }
        As[lc4 + 0][lrow] = av.x;
        As[lc4 + 1][lrow] = av.y;
        As[lc4 + 2][lrow] = av.z;
        As[lc4 + 3][lrow] = av.w;
        // --- stage W tile (rows always in range: grid.x == Ncols/64)
        float4 bv = *(const float4*)(W + (size_t)(bn + lrow) * 512 + kt + lc4);
        Bs[lc4 + 0][lrow] = bv.x;
        Bs[lc4 + 1][lrow] = bv.y;
        Bs[lc4 + 2][lrow] = bv.z;
        Bs[lc4 + 3][lrow] = bv.w;
        __syncthreads();

        #pragma unroll
        for (int kk = 0; kk < 16; ++kk) {
            float4 a4 = *(const float4*)&As[kk][ty * 4];
            float4 b4 = *(const float4*)&Bs[kk][tx * 4];
            acc[0][0] += a4.x * b4.x; acc[0][1] += a4.x * b4.y;
            acc[0][2] += a4.x * b4.z; acc[0][3] += a4.x * b4.w;
            acc[1][0] += a4.y * b4.x; acc[1][1] += a4.y * b4.y;
            acc[1][2] += a4.y * b4.z; acc[1][3] += a4.y * b4.w;
            acc[2][0] += a4.z * b4.x; acc[2][1] += a4.z * b4.y;
            acc[2][2] += a4.z * b4.z; acc[2][3] += a4.z * b4.w;
            acc[3][0] += a4.w * b4.x; acc[3][1] += a4.w * b4.y;
            acc[3][2] += a4.w * b4.z; acc[3][3] += a4.w * b4.w;
        }
        __syncthreads();
    }

    const int cbase = bn + tx * 4;
    #pragma unroll
    for (int i = 0; i < 4; ++i) {
        int r = bm + ty * 4 + i;
        if (r >= Mrows) break;
        float4 v;
        v.x = acc[i][0]; v.y = acc[i][1]; v.z = acc[i][2]; v.w = acc[i][3];
        if (bias) {
            v.x += bias[cbase + 0]; v.y += bias[cbase + 1];
            v.z += bias[cbase + 2]; v.w += bias[cbase + 3];
        }
        if (outMode == 0) {
            if (r >= clampStart) {
                v.x = fminf(fmaxf(v.x, -10.f), 10.f);
                v.y = fminf(fmaxf(v.y, -10.f), 10.f);
                v.z = fminf(fmaxf(v.z, -10.f), 10.f);
                v.w = fminf(fmaxf(v.w, -10.f), 10.f);
            }
            *(float4*)(out0 + (size_t)r * Ncols + cbase) = v;
        } else {
            if (cbase < 512)
                *(float4*)(out0 + (size_t)r * 512 + cbase) = v;
            else
                *(float4*)(out1 + (size_t)r * 512 + (cbase - 512)) = v;
        }
    }
}

// ---------------------------------------------------------------------------
// One block per (q, n) with n = b*H + h. 256 threads.
// scores[k] = (qu . K[k]) + (q in utt rows && k>=64 ? qv . posW[511-u+(k-64)] : 0)
// then *SCALE, mask, pad, softmax over 576, then attnT[q,b,h*64+hd] = probs . V
__global__ __launch_bounds__(256) void attn_kernel(
    const float* __restrict__ query,   // (560*16, 512) ws
    const float* __restrict__ keyOut,  // (576*16, 512) in d_out
    const float* __restrict__ valOut,  // (576*16, 512) in d_out
    const float* __restrict__ posW,    // (1023, 512) ws
    const float* __restrict__ pbu, const float* __restrict__ pbv,
    const void* __restrict__ maskPtr,
    const int* __restrict__ lengths,
    const int* __restrict__ maskMode,
    float* __restrict__ attnT)         // (560*16, 512) ws
{
    const int q = blockIdx.x;
    const int n = blockIdx.y;
    const int b = n >> 3, h = n & 7;
    const int tid = threadIdx.x;

    __shared__ float qu[64], qv[64];
    __shared__ float sc[576];
    __shared__ float red[256];

    const int mode = *maskMode;
    const int padStart = 64 + lengths[b];   // k >= KV - U + len  -> masked

    if (tid < 64) {
        float qf = query[((size_t)q * 16 + b) * 512 + h * 64 + tid];
        qu[tid] = qf + pbu[h * 64 + tid];
        qv[tid] = qf + pbv[h * 64 + tid];
    }
    __syncthreads();

    const bool hasBD = (q >= 32 && q < 544);
    const int u = q - 32;

    for (int k = tid; k < 576; k += 256) {
        const float* kp = keyOut + ((size_t)k * 16 + b) * 512 + h * 64;
        float ac = 0.f;
        #pragma unroll
        for (int i = 0; i < 64; ++i) ac += qu[i] * kp[i];
        float bd = 0.f;
        if (hasBD && k >= 64) {
            int p = 511 - u + (k - 64);          // rel_shift index, in [0,1022]
            const float* pp = posW + (size_t)p * 512 + h * 64;
            #pragma unroll
            for (int i = 0; i < 64; ++i) bd += qv[i] * pp[i];
        }
        float s = (ac + bd) * SCALE_F;
        size_t mi = (size_t)q * 576 + k;
        bool m;
        if (mode == 1)      m = ((const unsigned char*)maskPtr)[mi] != 0;
        else if (mode == 2) m = ((const float*)maskPtr)[mi] != 0.f;
        else                m = ((const int*)maskPtr)[mi] != 0;
        if (m || k >= padStart) s = NEG_INF_F;
        sc[k] = s;
    }
    __syncthreads();

    // block max
    float mx = -3.0e38f;
    for (int k = tid; k < 576; k += 256) mx = fmaxf(mx, sc[k]);
    red[tid] = mx; __syncthreads();
    for (int s2 = 128; s2 > 0; s2 >>= 1) {
        if (tid < s2) red[tid] = fmaxf(red[tid], red[tid + s2]);
        __syncthreads();
    }
    mx = red[0]; __syncthreads();

    // exp + block sum (unnormalized probs left in sc[])
    float sum = 0.f;
    for (int k = tid; k < 576; k += 256) {
        float e = expf(sc[k] - mx);
        sc[k] = e;
        sum += e;
    }
    red[tid] = sum; __syncthreads();
    for (int s2 = 128; s2 > 0; s2 >>= 1) {
        if (tid < s2) red[tid] += red[tid + s2];
        __syncthreads();
    }
    const float inv = 1.f / red[0];
    __syncthreads();

    // probs @ V : 4 k-chunks x 64 hd lanes
    const int hd = tid & 63, c = tid >> 6;
    float acc = 0.f;
    for (int k = c * 144; k < (c + 1) * 144; ++k)
        acc += sc[k] * valOut[((size_t)k * 16 + b) * 512 + h * 64 + hd];
    red[tid] = acc; __syncthreads();
    if (tid < 64) {
        float v = red[tid] + red[tid + 64] + red[tid + 128] + red[tid + 192];
        attnT[((size_t)q * 16 + b) * 512 + h * 64 + tid] = v * inv;
    }
}

// ---------------------------------------------------------------------------
extern "C" void kernel_launch(void* const* d_in, const int* in_sizes, int n_in,
                              void* d_out, int out_size, void* d_ws, size_t ws_size,
                              hipStream_t stream) {
    const float* utt     = (const float*)d_in[0];   // (512,16,512)
    const int*   lengths = (const int*)d_in[1];     // (16,)
    const float* rc      = (const float*)d_in[2];   // (32,16,512)
    const float* summ    = (const float*)d_in[3];   // (16,16,512)
    const float* mem     = (const float*)d_in[4];   // (32,16,512)
    const void*  mask    = d_in[5];                 // (560,576) bool-ish
    const float* pos_emb = (const float*)d_in[6];   // (1023,512)
    const float* Wq      = (const float*)d_in[7];
    const float* bq      = (const float*)d_in[8];
    const float* Wkv     = (const float*)d_in[9];   // (1024,512)
    const float* bkv     = (const float*)d_in[10];
    const float* Wo      = (const float*)d_in[11];
    const float* bo      = (const float*)d_in[12];
    const float* Wpos    = (const float*)d_in[13];
    const float* pbu     = (const float*)d_in[14];  // (8,64)
    const float* pbv     = (const float*)d_in[15];  // (8,64)

    float* out = (float*)d_out;
    // output layout (flat): out0 (544*16*512) | out1 (16*16*512) | key | val
    float* out0   = out;                 // rows 0..8959 contiguous incl. out1
    float* keyOut = out + 4587520;       // (576*16, 512)
    float* valOut = out + 9306112;       // (576*16, 512)

    int*   flag  = (int*)d_ws;
    float* wsf   = (float*)d_ws;
    float* query = wsf + 16;             // (8960, 512)
    float* posW  = query + 4587520;      // (1023, 512)
    float* attnT = posW + 523776;        // (8960, 512)

    detect_mask_kernel<<<1, 256, 0, stream>>>((const unsigned int*)mask,
                                              (560 * 576) / 4, flag);

    // query = [rc; utt; summ] @ Wq^T + bq
    gemm_kernel<<<dim3(512 / 64, 8960 / 64), 256, 0, stream>>>(
        rc, utt, summ, 512, 8704, 8960, Wq, bq, query, nullptr, 512, 0, 1 << 30);

    // kv = [mem; rc; utt] @ Wkv^T + bkv  -> key/val directly into d_out
    gemm_kernel<<<dim3(1024 / 64, 9216 / 64), 256, 0, stream>>>(
        mem, rc, utt, 512, 1024, 9216, Wkv, bkv, keyOut, valOut, 1024, 1, 1 << 30);

    // posW = pos_emb @ Wpos^T   (M=1023, needs row guard)
    gemm_kernel<<<dim3(512 / 64, 16), 256, 0, stream>>>(
        pos_emb, pos_emb, pos_emb, 1 << 30, 1 << 30, 1023, Wpos, nullptr,
        posW, nullptr, 512, 0, 1 << 30);

    // attention -> attnT
    attn_kernel<<<dim3(560, 128), 256, 0, stream>>>(
        query, keyOut, valOut, posW, pbu, pbv, mask, lengths, flag, attnT);

    // outputs = attnT @ Wo^T + bo ; rows >= 8704 clipped to [-10,10] (out_memory)
    gemm_kernel<<<dim3(512 / 64, 8960 / 64), 256, 0, stream>>>(
        attnT, attnT, attnT, 1 << 30, 1 << 30, 8960, Wo, bo, out0, nullptr,
        512, 0, 8704);
}

// Round 2
// 776.971 us; speedup vs baseline: 3.9831x; 3.9831x over previous
//
#include <hip/hip_runtime.h>
#include <math.h>

// EmformerAttention MI355X — round 1: MFMA bf16 attention, fp32 GEMMs.
// U=512 B=16 D=512 H=8 HD=64 R=32 S=16 M=32 -> Q=560 KV=576 PE=1023 N=128

#define NEG_INF_F (-100000000.0f)
#define SCALE_F   (0.125f)   // 64^-0.5

typedef short short8 __attribute__((ext_vector_type(8)));
typedef float f32x4  __attribute__((ext_vector_type(4)));

__device__ __forceinline__ unsigned short f2b(float f) {
    unsigned int u = __builtin_bit_cast(unsigned int, f);
    u = u + 0x7FFFu + ((u >> 16) & 1u);          // round-to-nearest-even
    return (unsigned short)(u >> 16);
}
__device__ __forceinline__ float b2f(unsigned short h) {
    unsigned int u = ((unsigned int)h) << 16;
    return __builtin_bit_cast(float, u);
}
__device__ __forceinline__ void st2(unsigned short* p, float a, float b) {
    *(unsigned int*)p = (unsigned int)f2b(a) | ((unsigned int)f2b(b) << 16);
}

// ---------------------------------------------------------------------------
__global__ void detect_mask_kernel(const unsigned int* __restrict__ m,
                                   int nwords, int* __restrict__ flagOut) {
    __shared__ int fF, fG;
    if (threadIdx.x == 0) { fF = 0; fG = 0; }
    __syncthreads();
    for (int i = threadIdx.x; i < nwords; i += blockDim.x) {
        unsigned int w = m[i];
        if (w == 0x3F800000u)      atomicOr(&fF, 1);
        else if (w > 1u)           atomicOr(&fG, 1);
    }
    __syncthreads();
    if (threadIdx.x == 0) *flagOut = fF ? 2 : (fG ? 1 : 0);
}

// ---------------------------------------------------------------------------
// fp32 GEMM: C[r,c] = sum_k A[r,k] * W[c,k] (+bias[c]), K=512.
__global__ __launch_bounds__(256) void gemm_kernel(
    const float* __restrict__ a0, const float* __restrict__ a1,
    const float* __restrict__ a2,
    int rb1, int rb2, int Mrows,
    const float* __restrict__ W, const float* __restrict__ bias,
    float* __restrict__ out0, float* __restrict__ out1,
    int Ncols, int outMode, int clampStart)
{
    const int tid = threadIdx.x;
    const int tx = tid & 15, ty = tid >> 4;
    const int bm = blockIdx.y * 64, bn = blockIdx.x * 64;

    __shared__ float As[16][68];
    __shared__ float Bs[16][68];

    float acc[4][4] = {{0.f}};
    const int lrow = tid >> 2;
    const int lc4  = (tid & 3) * 4;

    for (int kt = 0; kt < 512; kt += 16) {
        float4 av = make_float4(0.f, 0.f, 0.f, 0.f);
        {
            int r = bm + lrow;
            if (r < Mrows) {
                const float* src;
                if (r < rb1)      src = a0 + (size_t)r * 512;
                else if (r < rb2) src = a1 + (size_t)(r - rb1) * 512;
                else              src = a2 + (size_t)(r - rb2) * 512;
                av = *(const float4*)(src + kt + lc4);
            }
        }
        As[lc4 + 0][lrow] = av.x; As[lc4 + 1][lrow] = av.y;
        As[lc4 + 2][lrow] = av.z; As[lc4 + 3][lrow] = av.w;
        float4 bv = *(const float4*)(W + (size_t)(bn + lrow) * 512 + kt + lc4);
        Bs[lc4 + 0][lrow] = bv.x; Bs[lc4 + 1][lrow] = bv.y;
        Bs[lc4 + 2][lrow] = bv.z; Bs[lc4 + 3][lrow] = bv.w;
        __syncthreads();

        #pragma unroll
        for (int kk = 0; kk < 16; ++kk) {
            float4 a4 = *(const float4*)&As[kk][ty * 4];
            float4 b4 = *(const float4*)&Bs[kk][tx * 4];
            acc[0][0] += a4.x * b4.x; acc[0][1] += a4.x * b4.y;
            acc[0][2] += a4.x * b4.z; acc[0][3] += a4.x * b4.w;
            acc[1][0] += a4.y * b4.x; acc[1][1] += a4.y * b4.y;
            acc[1][2] += a4.y * b4.z; acc[1][3] += a4.y * b4.w;
            acc[2][0] += a4.z * b4.x; acc[2][1] += a4.z * b4.y;
            acc[2][2] += a4.z * b4.z; acc[2][3] += a4.z * b4.w;
            acc[3][0] += a4.w * b4.x; acc[3][1] += a4.w * b4.y;
            acc[3][2] += a4.w * b4.z; acc[3][3] += a4.w * b4.w;
        }
        __syncthreads();
    }

    const int cbase = bn + tx * 4;
    #pragma unroll
    for (int i = 0; i < 4; ++i) {
        int r = bm + ty * 4 + i;
        if (r >= Mrows) break;
        float4 v;
        v.x = acc[i][0]; v.y = acc[i][1]; v.z = acc[i][2]; v.w = acc[i][3];
        if (bias) {
            v.x += bias[cbase + 0]; v.y += bias[cbase + 1];
            v.z += bias[cbase + 2]; v.w += bias[cbase + 3];
        }
        if (outMode == 0) {
            if (r >= clampStart) {
                v.x = fminf(fmaxf(v.x, -10.f), 10.f);
                v.y = fminf(fmaxf(v.y, -10.f), 10.f);
                v.z = fminf(fmaxf(v.z, -10.f), 10.f);
                v.w = fminf(fmaxf(v.w, -10.f), 10.f);
            }
            *(float4*)(out0 + (size_t)r * Ncols + cbase) = v;
        } else {
            if (cbase < 512)
                *(float4*)(out0 + (size_t)r * 512 + cbase) = v;
            else
                *(float4*)(out1 + (size_t)r * 512 + (cbase - 512)) = v;
        }
    }
}

// ---------------------------------------------------------------------------
// MFMA attention. Block = (q-tile of 32, n=b*8+h). 256 threads = 4 waves.
// mfma_f32_16x16x32_bf16 layouts (HW-verified, learn_hip m89/m91/m120):
//   A: lane l -> A[m0+(l&15)][k0+(l>>4)*8+j], j=0..7  (16B contiguous)
//   B: lane l -> B[k0+(l>>4)*8+j][n0+(l&15)]          (= rows of B^T, 16B)
//   C/D: lane l, reg r -> row m0+(l>>4)*4+r, col n0+(l&15)
// LDS strides: stage rows 72 bf16 (144B, 16B-aligned, 2-way bank alias = free)
//              scores rows 584 bf16 (1168B, 16B-aligned, 2-way alias)
__global__ __launch_bounds__(256) void attn_mfma_kernel(
    const float* __restrict__ query,   // (560*16,512) ws fp32
    const float* __restrict__ keyOut,  // (576*16,512) d_out fp32
    const float* __restrict__ valOut,  // (576*16,512) d_out fp32
    const float* __restrict__ posW,    // (1023,512)   ws fp32
    const float* __restrict__ pbu, const float* __restrict__ pbv,
    const void* __restrict__ maskPtr,
    const int* __restrict__ lengths,
    const int* __restrict__ maskMode,
    float* __restrict__ attnT)         // (560*16,512) ws fp32
{
    __shared__ unsigned short sc[32 * 584];   // scores / P (bf16)
    __shared__ unsigned short Qu[32 * 72];
    __shared__ unsigned short Qv[32 * 72];
    __shared__ unsigned short stg[96 * 72];   // K tile / posW band / V^T tile
    __shared__ float red[32 * 8];
    __shared__ float rowv[32];                // row max, then 1/sum

    const int qt = blockIdx.x, n = blockIdx.y;
    const int b = n >> 3, h = n & 7;
    const int q0 = qt * 32;
    const int tid = threadIdx.x;
    const int w = tid >> 6, lane = tid & 63;
    const int l15 = lane & 15, l4 = lane >> 4;
    const bool hasBand = (qt >= 1 && qt <= 16);   // tiles fully inside utterance

    // ---- stage Qu = q + pos_bias_u, Qv = q + pos_bias_v (bf16, zero-pad q>=560)
    for (int i = tid; i < 512; i += 256) {
        int row = i >> 4, c4 = i & 15;
        int q = q0 + row;
        unsigned short* pu = &Qu[row * 72 + c4 * 4];
        unsigned short* pv = &Qv[row * 72 + c4 * 4];
        if (q < 560) {
            float4 v  = *(const float4*)(query + ((size_t)q * 16 + b) * 512 + h * 64 + c4 * 4);
            float4 bu = *(const float4*)(pbu + h * 64 + c4 * 4);
            float4 bv = *(const float4*)(pbv + h * 64 + c4 * 4);
            st2(pu,     v.x + bu.x, v.y + bu.y);
            st2(pu + 2, v.z + bu.z, v.w + bu.w);
            st2(pv,     v.x + bv.x, v.y + bv.y);
            st2(pv + 2, v.z + bv.z, v.w + bv.w);
        } else {
            *(unsigned int*)pu = 0u; *(unsigned int*)(pu + 2) = 0u;
            *(unsigned int*)pv = 0u; *(unsigned int*)(pv + 2) = 0u;
        }
    }

    // ---- scores: AC (+ banded BD) per 64-col k-tile
    for (int kt = 0; kt < 9; ++kt) {
        __syncthreads();                       // stg free from previous phase
        for (int i = tid; i < 1024; i += 256) {
            int row = i >> 4, c4 = i & 15;
            float4 v = *(const float4*)(keyOut + ((size_t)(kt * 64 + row) * 16 + b) * 512 + h * 64 + c4 * 4);
            unsigned short* p = &stg[row * 72 + c4 * 4];
            st2(p, v.x, v.y); st2(p + 2, v.z, v.w);
        }
        __syncthreads();
        #pragma unroll
        for (int s = 0; s < 2; ++s) {
            int ti = w * 2 + s, m0 = (ti >> 2) * 16, n0 = (ti & 3) * 16;
            f32x4 acc = {0.f, 0.f, 0.f, 0.f};
            #pragma unroll
            for (int kk = 0; kk < 2; ++kk) {
                short8 af = *(const short8*)&Qu[(m0 + l15) * 72 + kk * 32 + l4 * 8];
                short8 bf = *(const short8*)&stg[(n0 + l15) * 72 + kk * 32 + l4 * 8];
                acc = __builtin_amdgcn_mfma_f32_16x16x32_bf16(af, bf, acc, 0, 0, 0);
            }
            int col = kt * 64 + n0 + l15;
            #pragma unroll
            for (int r = 0; r < 4; ++r)
                sc[(m0 + l4 * 4 + r) * 584 + col] = f2b(acc[r]);
        }
        if (kt >= 1 && hasBand) {
            __syncthreads();                   // AC done reading stg + sc written
            // band rows p = pb + t, t in [0,96); used t = 31-du+dj in [0,94]
            int pb = 512 - q0 + (kt - 1) * 64;
            for (int i = tid; i < 1536; i += 256) {
                int row = i >> 4, c4 = i & 15;
                int p = pb + row;
                p = p < 0 ? 0 : (p > 1022 ? 1022 : p);   // clamped rows never used
                float4 v = *(const float4*)(posW + (size_t)p * 512 + h * 64 + c4 * 4);
                unsigned short* pp = &stg[row * 72 + c4 * 4];
                st2(pp, v.x, v.y); st2(pp + 2, v.z, v.w);
            }
            __syncthreads();
            #pragma unroll
            for (int s = 0; s < 3; ++s) {
                int ti = w * 3 + s;            // 12 tiles: 2 (du) x 6 (t)
                int m0 = (ti / 6) * 16, n0 = (ti % 6) * 16;
                f32x4 acc = {0.f, 0.f, 0.f, 0.f};
                #pragma unroll
                for (int kk = 0; kk < 2; ++kk) {
                    short8 af = *(const short8*)&Qv[(m0 + l15) * 72 + kk * 32 + l4 * 8];
                    short8 bf = *(const short8*)&stg[(n0 + l15) * 72 + kk * 32 + l4 * 8];
                    acc = __builtin_amdgcn_mfma_f32_16x16x32_bf16(af, bf, acc, 0, 0, 0);
                }
                int t = n0 + l15;
                #pragma unroll
                for (int r = 0; r < 4; ++r) {
                    int du = m0 + l4 * 4 + r;
                    int dj = t - 31 + du;      // t = 31-du+dj
                    if (dj >= 0 && dj < 64) {
                        int idx = du * 584 + kt * 64 + dj;
                        sc[idx] = f2b(b2f(sc[idx]) + acc[r]);  // unique (du,dj) per lane
                    }
                }
            }
        }
    }
    __syncthreads();

    // ---- softmax: scale, mask, pad; P (bf16) left unnormalized, 1/sum in rowv
    {
        const int row = tid >> 3, seg = tid & 7, c0 = seg * 72;
        const int q = q0 + row;
        const int padStart = 64 + lengths[b];
        const int mode = *maskMode;
        float mx = -3.0e38f;
        unsigned short* sr = &sc[row * 584];
        if (q < 560) {
            if (mode == 1) {
                const unsigned char* mp = (const unsigned char*)maskPtr + (size_t)q * 576;
                for (int c = c0; c < c0 + 72; ++c) {
                    float s = b2f(sr[c]) * SCALE_F;
                    if (mp[c] || c >= padStart) s = NEG_INF_F;
                    sr[c] = f2b(s); mx = fmaxf(mx, s);
                }
            } else if (mode == 2) {
                const float* mp = (const float*)maskPtr + (size_t)q * 576;
                for (int c = c0; c < c0 + 72; ++c) {
                    float s = b2f(sr[c]) * SCALE_F;
                    if (mp[c] != 0.f || c >= padStart) s = NEG_INF_F;
                    sr[c] = f2b(s); mx = fmaxf(mx, s);
                }
            } else {
                const int* mp = (const int*)maskPtr + (size_t)q * 576;
                for (int c = c0; c < c0 + 72; ++c) {
                    float s = b2f(sr[c]) * SCALE_F;
                    if (mp[c] || c >= padStart) s = NEG_INF_F;
                    sr[c] = f2b(s); mx = fmaxf(mx, s);
                }
            }
        } else {
            for (int c = c0; c < c0 + 72; ++c) {
                float s = b2f(sr[c]) * SCALE_F;
                sr[c] = f2b(s); mx = fmaxf(mx, s);
            }
        }
        red[row * 8 + seg] = mx;
    }
    __syncthreads();
    if (tid < 32) {
        float m = red[tid * 8];
        #pragma unroll
        for (int i = 1; i < 8; ++i) m = fmaxf(m, red[tid * 8 + i]);
        rowv[tid] = m;
    }
    __syncthreads();
    {
        const int row = tid >> 3, seg = tid & 7, c0 = seg * 72;
        float mx = rowv[row], lsum = 0.f;
        unsigned short* sr = &sc[row * 584];
        for (int c = c0; c < c0 + 72; ++c) {
            float e = __expf(b2f(sr[c]) - mx);
            sr[c] = f2b(e); lsum += e;
        }
        red[row * 8 + seg] = lsum;
    }
    __syncthreads();
    if (tid < 32) {
        float s = 0.f;
        #pragma unroll
        for (int i = 0; i < 8; ++i) s += red[tid * 8 + i];
        rowv[tid] = 1.f / s;
    }

    // ---- PV: O = P @ V, V staged transposed (V^T rows = hd)
    f32x4 oacc[2] = {{0.f, 0.f, 0.f, 0.f}, {0.f, 0.f, 0.f, 0.f}};
    for (int kt = 0; kt < 9; ++kt) {
        __syncthreads();
        for (int i = tid; i < 1024; i += 256) {
            int row = i >> 4, c4 = i & 15;   // row = local k
            float4 v = *(const float4*)(valOut + ((size_t)(kt * 64 + row) * 16 + b) * 512 + h * 64 + c4 * 4);
            stg[(c4 * 4 + 0) * 72 + row] = f2b(v.x);
            stg[(c4 * 4 + 1) * 72 + row] = f2b(v.y);
            stg[(c4 * 4 + 2) * 72 + row] = f2b(v.z);
            stg[(c4 * 4 + 3) * 72 + row] = f2b(v.w);
        }
        __syncthreads();
        #pragma unroll
        for (int s = 0; s < 2; ++s) {
            int ti = w * 2 + s, m0 = (ti >> 2) * 16, n0 = (ti & 3) * 16;
            #pragma unroll
            for (int kk = 0; kk < 2; ++kk) {
                short8 af = *(const short8*)&sc[(m0 + l15) * 584 + kt * 64 + kk * 32 + l4 * 8];
                short8 bf = *(const short8*)&stg[(n0 + l15) * 72 + kk * 32 + l4 * 8];
                oacc[s] = __builtin_amdgcn_mfma_f32_16x16x32_bf16(af, bf, oacc[s], 0, 0, 0);
            }
        }
    }

    // ---- epilogue: O * (1/sum) -> attnT[q,b,h*64+hd]
    #pragma unroll
    for (int s = 0; s < 2; ++s) {
        int ti = w * 2 + s, m0 = (ti >> 2) * 16, n0 = (ti & 3) * 16;
        #pragma unroll
        for (int r = 0; r < 4; ++r) {
            int row = m0 + l4 * 4 + r, q = q0 + row;
            if (q < 560)
                attnT[((size_t)q * 16 + b) * 512 + h * 64 + n0 + l15] = oacc[s][r] * rowv[row];
        }
    }
}

// ---------------------------------------------------------------------------
extern "C" void kernel_launch(void* const* d_in, const int* in_sizes, int n_in,
                              void* d_out, int out_size, void* d_ws, size_t ws_size,
                              hipStream_t stream) {
    const float* utt     = (const float*)d_in[0];
    const int*   lengths = (const int*)d_in[1];
    const float* rc      = (const float*)d_in[2];
    const float* summ    = (const float*)d_in[3];
    const float* mem     = (const float*)d_in[4];
    const void*  mask    = d_in[5];
    const float* pos_emb = (const float*)d_in[6];
    const float* Wq      = (const float*)d_in[7];
    const float* bq      = (const float*)d_in[8];
    const float* Wkv     = (const float*)d_in[9];
    const float* bkv     = (const float*)d_in[10];
    const float* Wo      = (const float*)d_in[11];
    const float* bo      = (const float*)d_in[12];
    const float* Wpos    = (const float*)d_in[13];
    const float* pbu     = (const float*)d_in[14];
    const float* pbv     = (const float*)d_in[15];

    float* out = (float*)d_out;
    float* out0   = out;
    float* keyOut = out + 4587520;
    float* valOut = out + 9306112;

    int*   flag  = (int*)d_ws;
    float* wsf   = (float*)d_ws;
    float* query = wsf + 16;
    float* posW  = query + 4587520;
    float* attnT = posW + 523776;

    detect_mask_kernel<<<1, 256, 0, stream>>>((const unsigned int*)mask,
                                              (560 * 576) / 4, flag);

    gemm_kernel<<<dim3(512 / 64, 8960 / 64), 256, 0, stream>>>(
        rc, utt, summ, 512, 8704, 8960, Wq, bq, query, nullptr, 512, 0, 1 << 30);

    gemm_kernel<<<dim3(1024 / 64, 9216 / 64), 256, 0, stream>>>(
        mem, rc, utt, 512, 1024, 9216, Wkv, bkv, keyOut, valOut, 1024, 1, 1 << 30);

    gemm_kernel<<<dim3(512 / 64, 16), 256, 0, stream>>>(
        pos_emb, pos_emb, pos_emb, 1 << 30, 1 << 30, 1023, Wpos, nullptr,
        posW, nullptr, 512, 0, 1 << 30);

    attn_mfma_kernel<<<dim3(18, 128), 256, 0, stream>>>(
        query, keyOut, valOut, posW, pbu, pbv, mask, lengths, flag, attnT);

    gemm_kernel<<<dim3(512 / 64, 8960 / 64), 256, 0, stream>>>(
        attnT, attnT, attnT, 1 << 30, 1 << 30, 8960, Wo, bo, out0, nullptr,
        512, 0, 8704);
}

// Round 3
// 435.763 us; speedup vs baseline: 7.1019x; 1.7830x over previous
//
#include <hip/hip_runtime.h>
#include <math.h>

// EmformerAttention MI355X — round 2: bf16 MFMA GEMMs + bf16-fed MFMA attention.
// U=512 B=16 D=512 H=8 HD=64 R=32 S=16 M=32 -> Q=560 KV=576 PE=1023 N=128

#define NEG_INF_F (-100000000.0f)
#define SCALE_F   (0.125f)

typedef short  short8 __attribute__((ext_vector_type(8)));
typedef float  f32x4  __attribute__((ext_vector_type(4)));
typedef unsigned short u16x4 __attribute__((ext_vector_type(4)));
typedef unsigned short u16x8 __attribute__((ext_vector_type(8)));

__device__ __forceinline__ unsigned short f2b(float f) {
    unsigned int u = __builtin_bit_cast(unsigned int, f);
    u = u + 0x7FFFu + ((u >> 16) & 1u);
    return (unsigned short)(u >> 16);
}
__device__ __forceinline__ float b2f(unsigned short h) {
    unsigned int u = ((unsigned int)h) << 16;
    return __builtin_bit_cast(float, u);
}

// ---------------------------------------------------------------------------
__global__ void detect_mask_kernel(const unsigned int* __restrict__ m,
                                   int nwords, int* __restrict__ flagOut) {
    __shared__ int fF, fG;
    if (threadIdx.x == 0) { fF = 0; fG = 0; }
    __syncthreads();
    for (int i = threadIdx.x; i < nwords; i += blockDim.x) {
        unsigned int w = m[i];
        if (w == 0x3F800000u)      atomicOr(&fF, 1);
        else if (w > 1u)           atomicOr(&fG, 1);
    }
    __syncthreads();
    if (threadIdx.x == 0) *flagOut = fF ? 2 : (fG ? 1 : 0);
}

// ---------------------------------------------------------------------------
// 9-array fp32 -> bf16 cast. blockIdx.y selects array; grid-stride in float4s.
__global__ __launch_bounds__(256) void conv9_kernel(
    const float* s0, const float* s1, const float* s2, const float* s3,
    const float* s4, const float* s5, const float* s6, const float* s7,
    const float* s8,
    unsigned short* d0, unsigned short* d1, unsigned short* d2,
    unsigned short* d3, unsigned short* d4, unsigned short* d5,
    unsigned short* d6, unsigned short* d7, unsigned short* d8,
    int n0, int n1, int n2, int n3, int n4, int n5, int n6, int n7, int n8)
{
    const float* ss[9] = {s0, s1, s2, s3, s4, s5, s6, s7, s8};
    unsigned short* dd[9] = {d0, d1, d2, d3, d4, d5, d6, d7, d8};
    int nn[9] = {n0, n1, n2, n3, n4, n5, n6, n7, n8};
    const int a = blockIdx.y;
    const float* s = ss[a];
    unsigned short* d = dd[a];
    const int nq = nn[a] >> 2;
    for (int i = blockIdx.x * 256 + threadIdx.x; i < nq; i += gridDim.x * 256) {
        float4 v = *(const float4*)(s + (size_t)i * 4);
        u16x4 o = {f2b(v.x), f2b(v.y), f2b(v.z), f2b(v.w)};
        *(u16x4*)(d + (size_t)i * 4) = o;
    }
}

// ---------------------------------------------------------------------------
// Vt transpose: valOut fp32 (kv*16+b, 512) -> VT bf16 [n][hd][576].
__global__ __launch_bounds__(256) void vt_kernel(const float* __restrict__ valOut,
                                                 unsigned short* __restrict__ VT) {
    __shared__ float t[64][65];
    const int kt = blockIdx.x, n = blockIdx.y;
    const int b = n >> 3, h = n & 7;
    const int tid = threadIdx.x;
    #pragma unroll
    for (int it = 0; it < 4; ++it) {
        int idx = tid + it * 256;          // 64 rows x 16 float4 chunks
        int kvl = idx >> 4, c = idx & 15;
        float4 v = *(const float4*)(valOut + ((size_t)(kt * 64 + kvl) * 16 + b) * 512 + h * 64 + c * 4);
        t[kvl][c * 4 + 0] = v.x; t[kvl][c * 4 + 1] = v.y;
        t[kvl][c * 4 + 2] = v.z; t[kvl][c * 4 + 3] = v.w;
    }
    __syncthreads();
    #pragma unroll
    for (int it = 0; it < 4; ++it) {
        int idx = tid + it * 256;
        int hd = idx >> 4, c = idx & 15;
        u16x4 o = {f2b(t[c * 4 + 0][hd]), f2b(t[c * 4 + 1][hd]),
                   f2b(t[c * 4 + 2][hd]), f2b(t[c * 4 + 3][hd])};
        *(u16x4*)(VT + ((size_t)n * 64 + hd) * 576 + kt * 64 + c * 4) = o;
    }
}

// ---------------------------------------------------------------------------
// bf16 MFMA GEMM: C[r,c] = sum_k A[r,k]*W[c,k] + bias[c].  K=512, BK=32,
// BM=BN=128, 256 thr / 4 waves, wave -> 64x64 quadrant (4x4 16x16 tiles).
// mode 0: out0[r*512+c] fp32, clamp +-10 for r>=clampStart (out-proj)
// mode 1: KV split: c<512 -> out0 fp32 + auxU=K bf16[n][kv][64]; else out1 fp32
// mode 2: Q-proj: auxU=Qu bf16[n][q][64] (+pbu), auxV=Qv (+pbv); no fp32 out
// mode 3: pos: auxU=posW bf16[h][p][64]
__global__ __launch_bounds__(256) void gemm_mfma(
    const unsigned short* __restrict__ a0, const unsigned short* __restrict__ a1,
    const unsigned short* __restrict__ a2,
    int rb1, int rb2, int Mrows,
    const unsigned short* __restrict__ Wt, const float* __restrict__ bias,
    float* __restrict__ out0, float* __restrict__ out1,
    unsigned short* __restrict__ auxU, unsigned short* __restrict__ auxV,
    const float* __restrict__ pbu, const float* __restrict__ pbv,
    int mode, int clampStart)
{
    __shared__ unsigned short As[128 * 40];   // rows of 32 bf16 + 8 pad
    __shared__ unsigned short Ws[128 * 40];

    const int tid = threadIdx.x;
    const int w = tid >> 6, lane = tid & 63;
    const int l15 = lane & 15, l4 = lane >> 4;
    const int wm = (w & 1) * 64, wn = (w >> 1) * 64;
    const int bm = blockIdx.y * 128, bn = blockIdx.x * 128;

    f32x4 acc[4][4];
    #pragma unroll
    for (int i = 0; i < 4; ++i)
        #pragma unroll
        for (int j = 0; j < 4; ++j) acc[i][j] = (f32x4){0.f, 0.f, 0.f, 0.f};

    for (int kt = 0; kt < 16; ++kt) {
        __syncthreads();
        #pragma unroll
        for (int it = 0; it < 2; ++it) {
            int cid = tid + it * 256;            // [0,512)
            int row = cid >> 2, c = cid & 3;
            int r = bm + row;
            u16x8 v = {0, 0, 0, 0, 0, 0, 0, 0};
            if (r < Mrows) {
                const unsigned short* src;
                if (r < rb1)      src = a0 + (size_t)r * 512;
                else if (r < rb2) src = a1 + (size_t)(r - rb1) * 512;
                else              src = a2 + (size_t)(r - rb2) * 512;
                v = *(const u16x8*)(src + kt * 32 + c * 8);
            }
            *(u16x8*)&As[row * 40 + c * 8] = v;
            u16x8 wv = *(const u16x8*)(Wt + (size_t)(bn + row) * 512 + kt * 32 + c * 8);
            *(u16x8*)&Ws[row * 40 + c * 8] = wv;
        }
        __syncthreads();

        short8 af[4], bf[4];
        #pragma unroll
        for (int t = 0; t < 4; ++t)
            af[t] = *(const short8*)&As[(wm + t * 16 + l15) * 40 + l4 * 8];
        #pragma unroll
        for (int t = 0; t < 4; ++t)
            bf[t] = *(const short8*)&Ws[(wn + t * 16 + l15) * 40 + l4 * 8];
        #pragma unroll
        for (int tm = 0; tm < 4; ++tm)
            #pragma unroll
            for (int tn = 0; tn < 4; ++tn)
                acc[tm][tn] = __builtin_amdgcn_mfma_f32_16x16x32_bf16(
                    af[tm], bf[tn], acc[tm][tn], 0, 0, 0);
    }

    // epilogue: C/D layout col = l15, row = l4*4+rr within each 16x16 tile
    #pragma unroll
    for (int tm = 0; tm < 4; ++tm) {
        #pragma unroll
        for (int tn = 0; tn < 4; ++tn) {
            const int col = bn + wn + tn * 16 + l15;
            const float bv = bias ? bias[col] : 0.f;
            #pragma unroll
            for (int rr = 0; rr < 4; ++rr) {
                const int row = bm + wm + tm * 16 + l4 * 4 + rr;
                if (row >= Mrows) continue;
                float v = acc[tm][tn][rr] + bv;
                if (mode == 0) {
                    if (row >= clampStart) v = fminf(fmaxf(v, -10.f), 10.f);
                    out0[(size_t)row * 512 + col] = v;
                } else if (mode == 1) {
                    if (col < 512) {
                        out0[(size_t)row * 512 + col] = v;
                        int kv = row >> 4, bb = row & 15, hh = col >> 6, hd = col & 63;
                        auxU[(((size_t)(bb * 8 + hh)) * 576 + kv) * 64 + hd] = f2b(v);
                    } else {
                        out1[(size_t)row * 512 + (col - 512)] = v;
                    }
                } else if (mode == 2) {
                    int q = row >> 4, bb = row & 15, hh = col >> 6, hd = col & 63;
                    size_t base = (((size_t)(bb * 8 + hh)) * 576 + q) * 64 + hd;
                    auxU[base] = f2b(v + pbu[col]);
                    auxV[base] = f2b(v + pbv[col]);
                } else {
                    int hh = col >> 6, hd = col & 63;
                    auxU[((size_t)hh * 1023 + row) * 64 + hd] = f2b(v);
                }
            }
        }
    }
}

// ---------------------------------------------------------------------------
// MFMA attention, all-bf16 operands. Block = (q-tile 32, n). 256 thr / 4 waves.
// Qu/Qv fragments loaded once into registers (each wave owns one m-tile).
// LDS 52.4 KB -> 3 blocks/CU.
__global__ __launch_bounds__(256) void attn_mfma_kernel(
    const unsigned short* __restrict__ Qu_g,  // [n][576][64] (q>=560 garbage)
    const unsigned short* __restrict__ Qv_g,  // [n][576][64]
    const unsigned short* __restrict__ K_g,   // [n][576][64]
    const unsigned short* __restrict__ VT_g,  // [n][64][576]
    const unsigned short* __restrict__ P_g,   // [8][1023][64]
    const void* __restrict__ maskPtr,
    const int* __restrict__ lengths,
    const int* __restrict__ maskMode,
    unsigned short* __restrict__ attnT)       // bf16 [(q*16+b)*512 + ch]
{
    __shared__ unsigned short sc[32 * 584];
    __shared__ unsigned short stg[96 * 72];
    __shared__ float red[256];
    __shared__ float rowv[32];

    const int qt = blockIdx.x, n = blockIdx.y;
    const int b = n >> 3, h = n & 7;
    const int q0 = qt * 32;
    const int tid = threadIdx.x;
    const int w = tid >> 6, lane = tid & 63;
    const int l15 = lane & 15, l4 = lane >> 4;
    const int mT = (w >> 1) * 16;             // wave's m-tile (AC and BD alike)
    const bool hasBand = (qt >= 1 && qt <= 16);

    // Qu/Qv fragments: fixed across all kt
    short8 quf[2], qvf[2];
    {
        size_t rb = ((size_t)n * 576 + q0 + mT + l15) * 64;
        quf[0] = *(const short8*)&Qu_g[rb + l4 * 8];
        quf[1] = *(const short8*)&Qu_g[rb + 32 + l4 * 8];
        qvf[0] = *(const short8*)&Qv_g[rb + l4 * 8];
        qvf[1] = *(const short8*)&Qv_g[rb + 32 + l4 * 8];
    }

    // ---- scores: AC (+ banded BD) per 64-col k-tile
    for (int kt = 0; kt < 9; ++kt) {
        __syncthreads();
        #pragma unroll
        for (int it = 0; it < 2; ++it) {
            int cid = tid + it * 256;         // 64 rows x 8 chunks
            int row = cid >> 3, c = cid & 7;
            u16x8 v = *(const u16x8*)&K_g[((size_t)n * 576 + kt * 64 + row) * 64 + c * 8];
            *(u16x8*)&stg[row * 72 + c * 8] = v;
        }
        __syncthreads();
        #pragma unroll
        for (int s = 0; s < 2; ++s) {
            int ti = w * 2 + s, n0 = (ti & 3) * 16;
            f32x4 acc = {0.f, 0.f, 0.f, 0.f};
            #pragma unroll
            for (int kk = 0; kk < 2; ++kk) {
                short8 bfr = *(const short8*)&stg[(n0 + l15) * 72 + kk * 32 + l4 * 8];
                acc = __builtin_amdgcn_mfma_f32_16x16x32_bf16(quf[kk], bfr, acc, 0, 0, 0);
            }
            int col = kt * 64 + n0 + l15;
            #pragma unroll
            for (int r = 0; r < 4; ++r)
                sc[(mT + l4 * 4 + r) * 584 + col] = f2b(acc[r]);
        }
        if (kt >= 1 && hasBand) {
            __syncthreads();
            int pb = 512 - q0 + (kt - 1) * 64;
            #pragma unroll
            for (int it = 0; it < 3; ++it) {
                int cid = tid + it * 256;     // 96 rows x 8 chunks
                int row = cid >> 3, c = cid & 7;
                int p = pb + row;
                p = p < 0 ? 0 : (p > 1022 ? 1022 : p);
                u16x8 v = *(const u16x8*)&P_g[((size_t)h * 1023 + p) * 64 + c * 8];
                *(u16x8*)&stg[row * 72 + c * 8] = v;
            }
            __syncthreads();
            #pragma unroll
            for (int s = 0; s < 3; ++s) {
                int ti = w * 3 + s, n0 = (ti % 6) * 16;
                f32x4 acc = {0.f, 0.f, 0.f, 0.f};
                #pragma unroll
                for (int kk = 0; kk < 2; ++kk) {
                    short8 bfr = *(const short8*)&stg[(n0 + l15) * 72 + kk * 32 + l4 * 8];
                    acc = __builtin_amdgcn_mfma_f32_16x16x32_bf16(qvf[kk], bfr, acc, 0, 0, 0);
                }
                int t = n0 + l15;
                #pragma unroll
                for (int r = 0; r < 4; ++r) {
                    int du = mT + l4 * 4 + r;
                    int dj = t - 31 + du;
                    if (dj >= 0 && dj < 64) {
                        int idx = du * 584 + kt * 64 + dj;
                        sc[idx] = f2b(b2f(sc[idx]) + acc[r]);
                    }
                }
            }
        }
    }
    __syncthreads();

    // ---- softmax (scale, mask, pad); P bf16 unnormalized, 1/sum in rowv
    {
        const int row = tid >> 3, seg = tid & 7, c0 = seg * 72;
        const int q = q0 + row;
        const int padStart = 64 + lengths[b];
        const int mode = *maskMode;
        float mx = -3.0e38f;
        unsigned short* sr = &sc[row * 584];
        if (q < 560) {
            if (mode == 1) {
                const unsigned char* mp = (const unsigned char*)maskPtr + (size_t)q * 576;
                for (int c = c0; c < c0 + 72; ++c) {
                    float s = b2f(sr[c]) * SCALE_F;
                    if (mp[c] || c >= padStart) s = NEG_INF_F;
                    sr[c] = f2b(s); mx = fmaxf(mx, s);
                }
            } else if (mode == 2) {
                const float* mp = (const float*)maskPtr + (size_t)q * 576;
                for (int c = c0; c < c0 + 72; ++c) {
                    float s = b2f(sr[c]) * SCALE_F;
                    if (mp[c] != 0.f || c >= padStart) s = NEG_INF_F;
                    sr[c] = f2b(s); mx = fmaxf(mx, s);
                }
            } else {
                const int* mp = (const int*)maskPtr + (size_t)q * 576;
                for (int c = c0; c < c0 + 72; ++c) {
                    float s = b2f(sr[c]) * SCALE_F;
                    if (mp[c] || c >= padStart) s = NEG_INF_F;
                    sr[c] = f2b(s); mx = fmaxf(mx, s);
                }
            }
        } else {
            for (int c = c0; c < c0 + 72; ++c) {
                float s = b2f(sr[c]) * SCALE_F;
                sr[c] = f2b(s); mx = fmaxf(mx, s);
            }
        }
        red[row * 8 + seg] = mx;
    }
    __syncthreads();
    if (tid < 32) {
        float m = red[tid * 8];
        #pragma unroll
        for (int i = 1; i < 8; ++i) m = fmaxf(m, red[tid * 8 + i]);
        rowv[tid] = m;
    }
    __syncthreads();
    {
        const int row = tid >> 3, seg = tid & 7, c0 = seg * 72;
        float mx = rowv[row], lsum = 0.f;
        unsigned short* sr = &sc[row * 584];
        for (int c = c0; c < c0 + 72; ++c) {
            float e = __expf(b2f(sr[c]) - mx);
            sr[c] = f2b(e); lsum += e;
        }
        red[row * 8 + seg] = lsum;
    }
    __syncthreads();
    if (tid < 32) {
        float s = 0.f;
        #pragma unroll
        for (int i = 0; i < 8; ++i) s += red[tid * 8 + i];
        rowv[tid] = 1.f / s;
    }

    // ---- PV
    f32x4 oacc[2] = {{0.f, 0.f, 0.f, 0.f}, {0.f, 0.f, 0.f, 0.f}};
    for (int kt = 0; kt < 9; ++kt) {
        __syncthreads();
        #pragma unroll
        for (int it = 0; it < 2; ++it) {
            int cid = tid + it * 256;
            int row = cid >> 3, c = cid & 7;   // row = hd
            u16x8 v = *(const u16x8*)&VT_g[((size_t)n * 64 + row) * 576 + kt * 64 + c * 8];
            *(u16x8*)&stg[row * 72 + c * 8] = v;
        }
        __syncthreads();
        #pragma unroll
        for (int s = 0; s < 2; ++s) {
            int ti = w * 2 + s, n0 = (ti & 3) * 16;
            #pragma unroll
            for (int kk = 0; kk < 2; ++kk) {
                short8 af = *(const short8*)&sc[(mT + l15) * 584 + kt * 64 + kk * 32 + l4 * 8];
                short8 bfr = *(const short8*)&stg[(n0 + l15) * 72 + kk * 32 + l4 * 8];
                oacc[s] = __builtin_amdgcn_mfma_f32_16x16x32_bf16(af, bfr, oacc[s], 0, 0, 0);
            }
        }
    }

    // ---- epilogue -> attnT bf16
    #pragma unroll
    for (int s = 0; s < 2; ++s) {
        int ti = w * 2 + s, n0 = (ti & 3) * 16;
        #pragma unroll
        for (int r = 0; r < 4; ++r) {
            int row = mT + l4 * 4 + r, q = q0 + row;
            if (q < 560)
                attnT[((size_t)q * 16 + b) * 512 + h * 64 + n0 + l15] =
                    f2b(oacc[s][r] * rowv[row]);
        }
    }
}

// ---------------------------------------------------------------------------
extern "C" void kernel_launch(void* const* d_in, const int* in_sizes, int n_in,
                              void* d_out, int out_size, void* d_ws, size_t ws_size,
                              hipStream_t stream) {
    const float* utt     = (const float*)d_in[0];
    const int*   lengths = (const int*)d_in[1];
    const float* rc      = (const float*)d_in[2];
    const float* summ    = (const float*)d_in[3];
    const float* mem     = (const float*)d_in[4];
    const void*  mask    = d_in[5];
    const float* pos_emb = (const float*)d_in[6];
    const float* Wq      = (const float*)d_in[7];
    const float* bq      = (const float*)d_in[8];
    const float* Wkv     = (const float*)d_in[9];
    const float* bkv     = (const float*)d_in[10];
    const float* Wo      = (const float*)d_in[11];
    const float* bo      = (const float*)d_in[12];
    const float* Wpos    = (const float*)d_in[13];
    const float* pbu     = (const float*)d_in[14];
    const float* pbv     = (const float*)d_in[15];

    float* out = (float*)d_out;
    float* out0   = out;
    float* keyOut = out + 4587520;
    float* valOut = out + 9306112;

    int* flag = (int*)d_ws;
    unsigned short* U = (unsigned short*)d_ws + 64;
    unsigned short* utt_bf  = U;                      // 4194304
    unsigned short* rc_bf   = utt_bf  + 4194304;      // 262144
    unsigned short* summ_bf = rc_bf   + 262144;       // 131072
    unsigned short* mem_bf  = summ_bf + 131072;       // 262144
    unsigned short* pose_bf = mem_bf  + 262144;       // 523776
    unsigned short* wq_bf   = pose_bf + 523776;       // 262144
    unsigned short* wkv_bf  = wq_bf   + 262144;       // 524288
    unsigned short* wo_bf   = wkv_bf  + 524288;       // 262144
    unsigned short* wpos_bf = wo_bf   + 262144;       // 262144
    unsigned short* Qu_bf   = wpos_bf + 262144;       // 4718592 = 128*576*64
    unsigned short* Qv_bf   = Qu_bf   + 4718592;
    unsigned short* K_bf    = Qv_bf   + 4718592;
    unsigned short* VT_bf   = K_bf    + 4718592;
    unsigned short* posW_bf = VT_bf   + 4718592;      // 523776 = 8*1023*64
    unsigned short* attnT_bf= posW_bf + 523776;       // 4587520

    detect_mask_kernel<<<1, 256, 0, stream>>>((const unsigned int*)mask,
                                              (560 * 576) / 4, flag);

    conv9_kernel<<<dim3(1024, 9), 256, 0, stream>>>(
        utt, rc, summ, mem, pos_emb, Wq, Wkv, Wo, Wpos,
        utt_bf, rc_bf, summ_bf, mem_bf, pose_bf, wq_bf, wkv_bf, wo_bf, wpos_bf,
        4194304, 262144, 131072, 262144, 523776, 262144, 524288, 262144, 262144);

    // Q-proj -> Qu/Qv bf16 (bias bq + pbu/pbv folded)
    gemm_mfma<<<dim3(4, 70), 256, 0, stream>>>(
        rc_bf, utt_bf, summ_bf, 512, 8704, 8960, wq_bf, bq,
        nullptr, nullptr, Qu_bf, Qv_bf, pbu, pbv, 2, 0);

    // KV-proj -> keyOut/valOut fp32 + K bf16
    gemm_mfma<<<dim3(8, 72), 256, 0, stream>>>(
        mem_bf, rc_bf, utt_bf, 512, 1024, 9216, wkv_bf, bkv,
        keyOut, valOut, K_bf, nullptr, nullptr, nullptr, 1, 0);

    // pos-proj -> posW bf16
    gemm_mfma<<<dim3(4, 8), 256, 0, stream>>>(
        pose_bf, pose_bf, pose_bf, 1 << 30, 1 << 30, 1023, wpos_bf, nullptr,
        nullptr, nullptr, posW_bf, nullptr, nullptr, nullptr, 3, 0);

    // V transpose -> VT bf16
    vt_kernel<<<dim3(9, 128), 256, 0, stream>>>(valOut, VT_bf);

    // attention -> attnT bf16
    attn_mfma_kernel<<<dim3(18, 128), 256, 0, stream>>>(
        Qu_bf, Qv_bf, K_bf, VT_bf, posW_bf, mask, lengths, flag, attnT_bf);

    // out-proj -> outputs 0,1 (clip rows >= 8704)
    gemm_mfma<<<dim3(4, 70), 256, 0, stream>>>(
        attnT_bf, attnT_bf, attnT_bf, 1 << 30, 1 << 30, 8960, wo_bf, bo,
        out0, nullptr, nullptr, nullptr, nullptr, nullptr, 0, 8704);
}

// Round 4
// 416.833 us; speedup vs baseline: 7.4244x; 1.0454x over previous
//
#include <hip/hip_runtime.h>
#include <math.h>

// EmformerAttention MI355X — round 3: parallel mask detect + barrier-free
// direct-global-fragment MFMA attention.
// U=512 B=16 D=512 H=8 HD=64 R=32 S=16 M=32 -> Q=560 KV=576 PE=1023 N=128

#define NEG_INF_F (-100000000.0f)
#define SCALE_F   (0.125f)

typedef short  short8 __attribute__((ext_vector_type(8)));
typedef float  f32x4  __attribute__((ext_vector_type(4)));
typedef unsigned short u16x4 __attribute__((ext_vector_type(4)));
typedef unsigned short u16x8 __attribute__((ext_vector_type(8)));

__device__ __forceinline__ unsigned short f2b(float f) {
    unsigned int u = __builtin_bit_cast(unsigned int, f);
    u = u + 0x7FFFu + ((u >> 16) & 1u);
    return (unsigned short)(u >> 16);
}
__device__ __forceinline__ float b2f(unsigned short h) {
    unsigned int u = ((unsigned int)h) << 16;
    return __builtin_bit_cast(float, u);
}

// ---------------------------------------------------------------------------
// Parallel mask dtype detection. flags[0]: float32 pattern seen; flags[1]:
// word>1 seen (byte-packed). Consumer: mode = flags[0]?2:(flags[1]?1:0).
__global__ __launch_bounds__(256) void detect_mask_kernel(
    const unsigned int* __restrict__ m, int nwords, int* __restrict__ flags) {
    __shared__ int fF, fG;
    if (threadIdx.x == 0) { fF = 0; fG = 0; }
    __syncthreads();
    int lF = 0, lG = 0;
    for (int i = blockIdx.x * 256 + threadIdx.x; i < nwords; i += gridDim.x * 256) {
        unsigned int w = m[i];
        if (w == 0x3F800000u)      lF = 1;
        else if (w > 1u)           lG = 1;
    }
    if (lF) atomicOr(&fF, 1);
    if (lG) atomicOr(&fG, 1);
    __syncthreads();
    if (threadIdx.x == 0) {
        if (fF) atomicOr(&flags[0], 1);
        if (fG) atomicOr(&flags[1], 1);
    }
}

// ---------------------------------------------------------------------------
// 9-array fp32 -> bf16 cast. blockIdx.y selects array; grid-stride in float4s.
__global__ __launch_bounds__(256) void conv9_kernel(
    const float* s0, const float* s1, const float* s2, const float* s3,
    const float* s4, const float* s5, const float* s6, const float* s7,
    const float* s8,
    unsigned short* d0, unsigned short* d1, unsigned short* d2,
    unsigned short* d3, unsigned short* d4, unsigned short* d5,
    unsigned short* d6, unsigned short* d7, unsigned short* d8,
    int n0, int n1, int n2, int n3, int n4, int n5, int n6, int n7, int n8)
{
    const float* ss[9] = {s0, s1, s2, s3, s4, s5, s6, s7, s8};
    unsigned short* dd[9] = {d0, d1, d2, d3, d4, d5, d6, d7, d8};
    int nn[9] = {n0, n1, n2, n3, n4, n5, n6, n7, n8};
    const int a = blockIdx.y;
    const float* s = ss[a];
    unsigned short* d = dd[a];
    const int nq = nn[a] >> 2;
    for (int i = blockIdx.x * 256 + threadIdx.x; i < nq; i += gridDim.x * 256) {
        float4 v = *(const float4*)(s + (size_t)i * 4);
        u16x4 o = {f2b(v.x), f2b(v.y), f2b(v.z), f2b(v.w)};
        *(u16x4*)(d + (size_t)i * 4) = o;
    }
}

// ---------------------------------------------------------------------------
// Vt transpose: valOut fp32 (kv*16+b, 512) -> VT bf16 [n][hd][576].
__global__ __launch_bounds__(256) void vt_kernel(const float* __restrict__ valOut,
                                                 unsigned short* __restrict__ VT) {
    __shared__ float t[64][65];
    const int kt = blockIdx.x, n = blockIdx.y;
    const int b = n >> 3, h = n & 7;
    const int tid = threadIdx.x;
    #pragma unroll
    for (int it = 0; it < 4; ++it) {
        int idx = tid + it * 256;
        int kvl = idx >> 4, c = idx & 15;
        float4 v = *(const float4*)(valOut + ((size_t)(kt * 64 + kvl) * 16 + b) * 512 + h * 64 + c * 4);
        t[kvl][c * 4 + 0] = v.x; t[kvl][c * 4 + 1] = v.y;
        t[kvl][c * 4 + 2] = v.z; t[kvl][c * 4 + 3] = v.w;
    }
    __syncthreads();
    #pragma unroll
    for (int it = 0; it < 4; ++it) {
        int idx = tid + it * 256;
        int hd = idx >> 4, c = idx & 15;
        u16x4 o = {f2b(t[c * 4 + 0][hd]), f2b(t[c * 4 + 1][hd]),
                   f2b(t[c * 4 + 2][hd]), f2b(t[c * 4 + 3][hd])};
        *(u16x4*)(VT + ((size_t)n * 64 + hd) * 576 + kt * 64 + c * 4) = o;
    }
}

// ---------------------------------------------------------------------------
// bf16 MFMA GEMM (see round 2). K=512, BK=32, BM=BN=128.
__global__ __launch_bounds__(256) void gemm_mfma(
    const unsigned short* __restrict__ a0, const unsigned short* __restrict__ a1,
    const unsigned short* __restrict__ a2,
    int rb1, int rb2, int Mrows,
    const unsigned short* __restrict__ Wt, const float* __restrict__ bias,
    float* __restrict__ out0, float* __restrict__ out1,
    unsigned short* __restrict__ auxU, unsigned short* __restrict__ auxV,
    const float* __restrict__ pbu, const float* __restrict__ pbv,
    int mode, int clampStart)
{
    __shared__ unsigned short As[128 * 40];
    __shared__ unsigned short Ws[128 * 40];

    const int tid = threadIdx.x;
    const int w = tid >> 6, lane = tid & 63;
    const int l15 = lane & 15, l4 = lane >> 4;
    const int wm = (w & 1) * 64, wn = (w >> 1) * 64;
    const int bm = blockIdx.y * 128, bn = blockIdx.x * 128;

    f32x4 acc[4][4];
    #pragma unroll
    for (int i = 0; i < 4; ++i)
        #pragma unroll
        for (int j = 0; j < 4; ++j) acc[i][j] = (f32x4){0.f, 0.f, 0.f, 0.f};

    for (int kt = 0; kt < 16; ++kt) {
        __syncthreads();
        #pragma unroll
        for (int it = 0; it < 2; ++it) {
            int cid = tid + it * 256;
            int row = cid >> 2, c = cid & 3;
            int r = bm + row;
            u16x8 v = {0, 0, 0, 0, 0, 0, 0, 0};
            if (r < Mrows) {
                const unsigned short* src;
                if (r < rb1)      src = a0 + (size_t)r * 512;
                else if (r < rb2) src = a1 + (size_t)(r - rb1) * 512;
                else              src = a2 + (size_t)(r - rb2) * 512;
                v = *(const u16x8*)(src + kt * 32 + c * 8);
            }
            *(u16x8*)&As[row * 40 + c * 8] = v;
            u16x8 wv = *(const u16x8*)(Wt + (size_t)(bn + row) * 512 + kt * 32 + c * 8);
            *(u16x8*)&Ws[row * 40 + c * 8] = wv;
        }
        __syncthreads();

        short8 af[4], bf[4];
        #pragma unroll
        for (int t = 0; t < 4; ++t)
            af[t] = *(const short8*)&As[(wm + t * 16 + l15) * 40 + l4 * 8];
        #pragma unroll
        for (int t = 0; t < 4; ++t)
            bf[t] = *(const short8*)&Ws[(wn + t * 16 + l15) * 40 + l4 * 8];
        #pragma unroll
        for (int tm = 0; tm < 4; ++tm)
            #pragma unroll
            for (int tn = 0; tn < 4; ++tn)
                acc[tm][tn] = __builtin_amdgcn_mfma_f32_16x16x32_bf16(
                    af[tm], bf[tn], acc[tm][tn], 0, 0, 0);
    }

    #pragma unroll
    for (int tm = 0; tm < 4; ++tm) {
        #pragma unroll
        for (int tn = 0; tn < 4; ++tn) {
            const int col = bn + wn + tn * 16 + l15;
            const float bv = bias ? bias[col] : 0.f;
            #pragma unroll
            for (int rr = 0; rr < 4; ++rr) {
                const int row = bm + wm + tm * 16 + l4 * 4 + rr;
                if (row >= Mrows) continue;
                float v = acc[tm][tn][rr] + bv;
                if (mode == 0) {
                    if (row >= clampStart) v = fminf(fmaxf(v, -10.f), 10.f);
                    out0[(size_t)row * 512 + col] = v;
                } else if (mode == 1) {
                    if (col < 512) {
                        out0[(size_t)row * 512 + col] = v;
                        int kv = row >> 4, bb = row & 15, hh = col >> 6, hd = col & 63;
                        auxU[(((size_t)(bb * 8 + hh)) * 576 + kv) * 64 + hd] = f2b(v);
                    } else {
                        out1[(size_t)row * 512 + (col - 512)] = v;
                    }
                } else if (mode == 2) {
                    int q = row >> 4, bb = row & 15, hh = col >> 6, hd = col & 63;
                    size_t base = (((size_t)(bb * 8 + hh)) * 576 + q) * 64 + hd;
                    auxU[base] = f2b(v + pbu[col]);
                    auxV[base] = f2b(v + pbv[col]);
                } else {
                    int hh = col >> 6, hd = col & 63;
                    auxU[((size_t)hh * 1023 + row) * 64 + hd] = f2b(v);
                }
            }
        }
    }
}

// ---------------------------------------------------------------------------
// MFMA attention v3: direct-global B-fragments, wave-private quadrants,
// barrier-free score/PV phases. Block = (q-tile 32, n). 256 thr / 4 waves.
// Wave w: rows [mT, mT+16), cols [c0, c0+32) of each 64-col k-tile.
// LDS ~38.5 KB -> 4 blocks/CU.
__global__ __launch_bounds__(256) void attn_mfma_kernel(
    const unsigned short* __restrict__ Qu_g,  // [n][576][64]
    const unsigned short* __restrict__ Qv_g,  // [n][576][64]
    const unsigned short* __restrict__ K_g,   // [n][576][64]
    const unsigned short* __restrict__ VT_g,  // [n][64][576]
    const unsigned short* __restrict__ P_g,   // [8][1023][64]
    const void* __restrict__ maskPtr,
    const int* __restrict__ lengths,
    const int* __restrict__ maskFlags,
    unsigned short* __restrict__ attnT)       // bf16 [(q*16+b)*512 + ch]
{
    __shared__ unsigned short sc[32 * 584];
    __shared__ float red[256];
    __shared__ float rowv[32];

    const int qt = blockIdx.x, n = blockIdx.y;
    const int b = n >> 3, h = n & 7;
    const int q0 = qt * 32;
    const int tid = threadIdx.x;
    const int w = tid >> 6, lane = tid & 63;
    const int l15 = lane & 15, l4 = lane >> 4;
    const int mT = (w >> 1) * 16;             // wave's row half
    const int c0 = (w & 1) * 32;              // wave's col half (per 64-col tile)
    const bool hasBand = (qt >= 1 && qt <= 16);

    // Qu/Qv A-fragments (wave-fixed)
    short8 quf[2], qvf[2];
    {
        size_t rb = ((size_t)n * 576 + q0 + mT + l15) * 64;
        quf[0] = *(const short8*)&Qu_g[rb + l4 * 8];
        quf[1] = *(const short8*)&Qu_g[rb + 32 + l4 * 8];
        qvf[0] = *(const short8*)&Qv_g[rb + l4 * 8];
        qvf[1] = *(const short8*)&Qv_g[rb + 32 + l4 * 8];
    }

    // ---- scores: AC (+ banded BD), barrier-free (wave-private quadrants)
    const unsigned short* Kn = K_g + (size_t)n * 576 * 64;
    const unsigned short* Ph = P_g + (size_t)h * 1023 * 64;
    for (int kt = 0; kt < 9; ++kt) {
        #pragma unroll
        for (int s = 0; s < 2; ++s) {
            const int n0 = c0 + s * 16;
            f32x4 acc = {0.f, 0.f, 0.f, 0.f};
            #pragma unroll
            for (int kk = 0; kk < 2; ++kk) {
                short8 bfr = *(const short8*)&Kn[((size_t)(kt * 64 + n0 + l15)) * 64 + kk * 32 + l4 * 8];
                acc = __builtin_amdgcn_mfma_f32_16x16x32_bf16(quf[kk], bfr, acc, 0, 0, 0);
            }
            const int col = kt * 64 + n0 + l15;
            #pragma unroll
            for (int r = 0; r < 4; ++r)
                sc[(mT + l4 * 4 + r) * 584 + col] = f2b(acc[r]);
        }
        if (kt >= 1 && hasBand) {
            const int pb = 512 - q0 + (kt - 1) * 64;   // p = pb + t
            const int t0base = 16 - mT + c0;           // 16-aligned
            #pragma unroll
            for (int s = 0; s < 3; ++s) {
                const int t0 = t0base + s * 16;
                f32x4 acc = {0.f, 0.f, 0.f, 0.f};
                int p = pb + t0 + l15;
                p = p < 0 ? 0 : (p > 1022 ? 1022 : p); // clamped rows fail dj guard
                #pragma unroll
                for (int kk = 0; kk < 2; ++kk) {
                    short8 bfr = *(const short8*)&Ph[(size_t)p * 64 + kk * 32 + l4 * 8];
                    acc = __builtin_amdgcn_mfma_f32_16x16x32_bf16(qvf[kk], bfr, acc, 0, 0, 0);
                }
                const int t = t0 + l15;
                #pragma unroll
                for (int r = 0; r < 4; ++r) {
                    const int du = mT + l4 * 4 + r;    // row in [mT, mT+16)
                    const int dj = t - 31 + du;
                    if (dj >= c0 && dj < c0 + 32) {    // own quadrant only
                        const int idx = du * 584 + kt * 64 + dj;
                        sc[idx] = f2b(b2f(sc[idx]) + acc[r]);
                    }
                }
            }
        }
    }
    __syncthreads();

    // ---- softmax (scale, mask, pad); P bf16 unnormalized, 1/sum in rowv
    {
        const int row = tid >> 3, seg = tid & 7, cc0 = seg * 72;
        const int q = q0 + row;
        const int padStart = 64 + lengths[b];
        const int mode = maskFlags[0] ? 2 : (maskFlags[1] ? 1 : 0);
        float mx = -3.0e38f;
        unsigned short* sr = &sc[row * 584];
        if (q < 560) {
            if (mode == 1) {
                const unsigned char* mp = (const unsigned char*)maskPtr + (size_t)q * 576;
                for (int c = cc0; c < cc0 + 72; ++c) {
                    float s = b2f(sr[c]) * SCALE_F;
                    if (mp[c] || c >= padStart) s = NEG_INF_F;
                    sr[c] = f2b(s); mx = fmaxf(mx, s);
                }
            } else if (mode == 2) {
                const float* mp = (const float*)maskPtr + (size_t)q * 576;
                for (int c = cc0; c < cc0 + 72; ++c) {
                    float s = b2f(sr[c]) * SCALE_F;
                    if (mp[c] != 0.f || c >= padStart) s = NEG_INF_F;
                    sr[c] = f2b(s); mx = fmaxf(mx, s);
                }
            } else {
                const int* mp = (const int*)maskPtr + (size_t)q * 576;
                for (int c = cc0; c < cc0 + 72; ++c) {
                    float s = b2f(sr[c]) * SCALE_F;
                    if (mp[c] || c >= padStart) s = NEG_INF_F;
                    sr[c] = f2b(s); mx = fmaxf(mx, s);
                }
            }
        } else {
            for (int c = cc0; c < cc0 + 72; ++c) {
                float s = b2f(sr[c]) * SCALE_F;
                sr[c] = f2b(s); mx = fmaxf(mx, s);
            }
        }
        red[row * 8 + seg] = mx;
    }
    __syncthreads();
    if (tid < 32) {
        float m = red[tid * 8];
        #pragma unroll
        for (int i = 1; i < 8; ++i) m = fmaxf(m, red[tid * 8 + i]);
        rowv[tid] = m;
    }
    __syncthreads();
    {
        const int row = tid >> 3, seg = tid & 7, cc0 = seg * 72;
        float mx = rowv[row], lsum = 0.f;
        unsigned short* sr = &sc[row * 584];
        for (int c = cc0; c < cc0 + 72; ++c) {
            float e = __expf(b2f(sr[c]) - mx);
            sr[c] = f2b(e); lsum += e;
        }
        red[row * 8 + seg] = lsum;
    }
    __syncthreads();
    if (tid < 32) {
        float s = 0.f;
        #pragma unroll
        for (int i = 0; i < 8; ++i) s += red[tid * 8 + i];
        rowv[tid] = 1.f / s;
    }
    __syncthreads();

    // ---- PV: barrier-free, direct-global VT B-frags; wave quadrant = 16x32
    f32x4 oacc[2] = {{0.f, 0.f, 0.f, 0.f}, {0.f, 0.f, 0.f, 0.f}};
    const unsigned short* VTn = VT_g + (size_t)n * 64 * 576;
    for (int kt = 0; kt < 9; ++kt) {
        #pragma unroll
        for (int s = 0; s < 2; ++s) {
            const int n0 = c0 + s * 16;
            #pragma unroll
            for (int kk = 0; kk < 2; ++kk) {
                short8 af = *(const short8*)&sc[(mT + l15) * 584 + kt * 64 + kk * 32 + l4 * 8];
                short8 bfr = *(const short8*)&VTn[((size_t)(n0 + l15)) * 576 + kt * 64 + kk * 32 + l4 * 8];
                oacc[s] = __builtin_amdgcn_mfma_f32_16x16x32_bf16(af, bfr, oacc[s], 0, 0, 0);
            }
        }
    }

    // ---- epilogue -> attnT bf16
    #pragma unroll
    for (int s = 0; s < 2; ++s) {
        const int n0 = c0 + s * 16;
        #pragma unroll
        for (int r = 0; r < 4; ++r) {
            const int row = mT + l4 * 4 + r, q = q0 + row;
            if (q < 560)
                attnT[((size_t)q * 16 + b) * 512 + h * 64 + n0 + l15] =
                    f2b(oacc[s][r] * rowv[row]);
        }
    }
}

// ---------------------------------------------------------------------------
extern "C" void kernel_launch(void* const* d_in, const int* in_sizes, int n_in,
                              void* d_out, int out_size, void* d_ws, size_t ws_size,
                              hipStream_t stream) {
    const float* utt     = (const float*)d_in[0];
    const int*   lengths = (const int*)d_in[1];
    const float* rc      = (const float*)d_in[2];
    const float* summ    = (const float*)d_in[3];
    const float* mem     = (const float*)d_in[4];
    const void*  mask    = d_in[5];
    const float* pos_emb = (const float*)d_in[6];
    const float* Wq      = (const float*)d_in[7];
    const float* bq      = (const float*)d_in[8];
    const float* Wkv     = (const float*)d_in[9];
    const float* bkv     = (const float*)d_in[10];
    const float* Wo      = (const float*)d_in[11];
    const float* bo      = (const float*)d_in[12];
    const float* Wpos    = (const float*)d_in[13];
    const float* pbu     = (const float*)d_in[14];
    const float* pbv     = (const float*)d_in[15];

    float* out = (float*)d_out;
    float* out0   = out;
    float* keyOut = out + 4587520;
    float* valOut = out + 9306112;

    int* flags = (int*)d_ws;
    unsigned short* U = (unsigned short*)d_ws + 64;
    unsigned short* utt_bf  = U;
    unsigned short* rc_bf   = utt_bf  + 4194304;
    unsigned short* summ_bf = rc_bf   + 262144;
    unsigned short* mem_bf  = summ_bf + 131072;
    unsigned short* pose_bf = mem_bf  + 262144;
    unsigned short* wq_bf   = pose_bf + 523776;
    unsigned short* wkv_bf  = wq_bf   + 262144;
    unsigned short* wo_bf   = wkv_bf  + 524288;
    unsigned short* wpos_bf = wo_bf   + 262144;
    unsigned short* Qu_bf   = wpos_bf + 262144;
    unsigned short* Qv_bf   = Qu_bf   + 4718592;
    unsigned short* K_bf    = Qv_bf   + 4718592;
    unsigned short* VT_bf   = K_bf    + 4718592;
    unsigned short* posW_bf = VT_bf   + 4718592;
    unsigned short* attnT_bf= posW_bf + 523776;

    hipMemsetAsync(flags, 0, 2 * sizeof(int), stream);
    detect_mask_kernel<<<158, 256, 0, stream>>>((const unsigned int*)mask,
                                                (560 * 576) / 4, flags);

    conv9_kernel<<<dim3(1024, 9), 256, 0, stream>>>(
        utt, rc, summ, mem, pos_emb, Wq, Wkv, Wo, Wpos,
        utt_bf, rc_bf, summ_bf, mem_bf, pose_bf, wq_bf, wkv_bf, wo_bf, wpos_bf,
        4194304, 262144, 131072, 262144, 523776, 262144, 524288, 262144, 262144);

    gemm_mfma<<<dim3(4, 70), 256, 0, stream>>>(
        rc_bf, utt_bf, summ_bf, 512, 8704, 8960, wq_bf, bq,
        nullptr, nullptr, Qu_bf, Qv_bf, pbu, pbv, 2, 0);

    gemm_mfma<<<dim3(8, 72), 256, 0, stream>>>(
        mem_bf, rc_bf, utt_bf, 512, 1024, 9216, wkv_bf, bkv,
        keyOut, valOut, K_bf, nullptr, nullptr, nullptr, 1, 0);

    gemm_mfma<<<dim3(4, 8), 256, 0, stream>>>(
        pose_bf, pose_bf, pose_bf, 1 << 30, 1 << 30, 1023, wpos_bf, nullptr,
        nullptr, nullptr, posW_bf, nullptr, nullptr, nullptr, 3, 0);

    vt_kernel<<<dim3(9, 128), 256, 0, stream>>>(valOut, VT_bf);

    attn_mfma_kernel<<<dim3(18, 128), 256, 0, stream>>>(
        Qu_bf, Qv_bf, K_bf, VT_bf, posW_bf, mask, lengths, flags, attnT_bf);

    gemm_mfma<<<dim3(4, 70), 256, 0, stream>>>(
        attnT_bf, attnT_bf, attnT_bf, 1 << 30, 1 << 30, 8960, wo_bf, bo,
        out0, nullptr, nullptr, nullptr, nullptr, nullptr, 0, 8704);
}